// Round 10
// baseline (314.350 us; speedup 1.0000x reference)
//
#include <hip/hip_runtime.h>
#include <cstdint>
#include <cstddef>

#define S_LEN   4096
#define D_MODEL 768
#define N_HEADS 12
#define HEAD_DIM 64
#define FF_DIM  3072
#define B_SZ    2
#define M_ROWS  (B_SZ * S_LEN)   // 8192
#define QKV_N   (3 * D_MODEL)    // 2304

typedef unsigned short u16;
typedef __attribute__((ext_vector_type(8))) __bf16 bf16x8;
typedef __attribute__((ext_vector_type(4))) float  f32x4;

__device__ __forceinline__ float bf2f(u16 u) {
    union { unsigned u32; float f; } cv; cv.u32 = ((unsigned)u) << 16; return cv.f;
}
__device__ __forceinline__ u16 f2bf(float f) {
    __bf16 b = (__bf16)f;
    union { __bf16 b; u16 u; } cv; cv.b = b; return cv.u;
}
__device__ __forceinline__ float gelu_fast(float x) {
    float x2 = x * x;
    float u  = x * fmaf(0.035677408f, x2, 0.7978845608f);
    float e  = __expf(-2.f * u);
    return x * __builtin_amdgcn_rcpf(1.f + e);
}
// async global->LDS, 16B per lane. LDS dest is wave-uniform base + lane*16.
__device__ __forceinline__ void async16(const void* g, void* l) {
    __builtin_amdgcn_global_load_lds(
        (const __attribute__((address_space(1))) unsigned int*)g,
        (__attribute__((address_space(3))) unsigned int*)l, 16, 0, 0);
}

// ---------------------------------------------------------------------------
// PREP (one launch, 2353 blocks): fuses
//   - 3x weight transposes fp32[R,C] -> bf16[C,R]  (ids 0..1583, 64x64 tiles)
//   - qkv bias concat                              (id 1584)
//   - x fp32 -> bf16                               (ids 1585..2352)
// NOTE (R6 lesson): no per-lane rotated e-order (runtime el[] index ->
// scratch, rule #20). Static e-order kept.
// ---------------------------------------------------------------------------
__global__ __launch_bounds__(256) void prep(
    const float* __restrict__ x,
    const float* __restrict__ Wq, const float* __restrict__ Wk,
    const float* __restrict__ Wv,
    const float* __restrict__ W1, const float* __restrict__ W2,
    const float* __restrict__ bq, const float* __restrict__ bk,
    const float* __restrict__ bv,
    u16* __restrict__ xbf, u16* __restrict__ WqkvT, u16* __restrict__ W1T,
    u16* __restrict__ W2T, float* __restrict__ biasqkv)
{
    __shared__ __align__(16) u16 T[64 * 72];
    const int id = blockIdx.x;
    const int t = threadIdx.x;

    if (id < 1584) {
        // ---- transpose tile jobs ----
        const float* in; u16* o_; int C, R, tx, ty;
        if (id < 432) {
            const int z = id / 144, tile = id % 144;
            in = (z == 0) ? Wq : (z == 1) ? Wk : Wv;
            o_ = WqkvT + (size_t)z * 768 * 768;
            R = 768; C = 768; tx = tile % 12; ty = tile / 12;
        } else if (id < 1008) {
            const int tile = id - 432;
            in = W1; o_ = W1T; R = 768; C = 3072; tx = tile % 48; ty = tile / 48;
        } else {
            const int tile = id - 1008;
            in = W2; o_ = W2T; R = 3072; C = 768; tx = tile % 12; ty = tile / 12;
        }
        const int r0 = ty * 64, c0 = tx * 64;
        for (int v = t; v < 512; v += 256) {
            int rr = v >> 3, c8 = (v & 7) * 8;
            const float* p = in + (size_t)(r0 + rr) * C + c0 + c8;
            float4 a = *(const float4*)p;
            float4 b = *(const float4*)(p + 4);
            union { uint4 q; u16 el[8]; } o;
            o.el[0] = f2bf(a.x); o.el[1] = f2bf(a.y);
            o.el[2] = f2bf(a.z); o.el[3] = f2bf(a.w);
            o.el[4] = f2bf(b.x); o.el[5] = f2bf(b.y);
            o.el[6] = f2bf(b.z); o.el[7] = f2bf(b.w);
            *(uint4*)&T[rr * 72 + c8] = o.q;
        }
        __syncthreads();
        for (int v = t; v < 512; v += 256) {
            int cc = v >> 3, r8 = (v & 7) * 8;
            union { uint4 q; u16 el[8]; } tmp;
            #pragma unroll
            for (int e = 0; e < 8; ++e) tmp.el[e] = T[(r8 + e) * 72 + cc];
            *(uint4*)&o_[(size_t)(c0 + cc) * R + r0 + r8] = tmp.q;
        }
    } else if (id == 1584) {
        // ---- qkv bias concat ----
        for (int i = t; i < 768; i += 256) {
            biasqkv[i]        = bq[i];
            biasqkv[768 + i]  = bk[i];
            biasqkv[1536 + i] = bv[i];
        }
    } else {
        // ---- x fp32 -> bf16, 4 vec8 per thread ----
        const long c = id - 1585;
        #pragma unroll
        for (int j = 0; j < 4; ++j) {
            const long i = c * 1024 + j * 256 + t;   // vec8 index, < 786432
            const float* p = x + i * 8;
            float4 a = *(const float4*)p;
            float4 b = *(const float4*)(p + 4);
            union { uint4 q; u16 el[8]; } o;
            o.el[0] = f2bf(a.x); o.el[1] = f2bf(a.y);
            o.el[2] = f2bf(a.z); o.el[3] = f2bf(a.w);
            o.el[4] = f2bf(b.x); o.el[5] = f2bf(b.y);
            o.el[6] = f2bf(b.z); o.el[7] = f2bf(b.w);
            ((uint4*)xbf)[i] = o.q;
        }
    }
}

// ---------------------------------------------------------------------------
// MFMA GEMM: C[M,N] = A[M,K] @ BT[N,K]^T + bias, optional GELU.
// bf16 in, fp32 acc, output bf16 (ofp32=0) or fp32 (ofp32=1).
// Tile TM x 128 (TM = MI*32), BK=64, 4 waves in 2x2 quadrant layout.
// XOR-swizzled LDS chunks (conflict-free ds_read_b128).
//
// R10 XCD remap: m FASTEST within XCD. Old order (n fastest) made the
// concurrent per-XCD cohort share one A m-panel but cycle the ENTIRE B
// matrix (FF1: 4.7 MB) -> working set > 4 MB per-XCD L2 -> B re-fetched
// per m-round (measured FF1 FETCH 49-63 MB vs ~17 ideal). m-fastest:
// cohort shares one B-panel (0.2 MB) + the XCD's A slice (1.6 MB) ->
// both L2-resident -> staging loads become L2 hits (200 vs 900 cyc) on
// the barrier-drain critical path. Still bijective.
//
// PF=1 (FF1): prefetch double-buffer (A/B-confirmed -2.5us/dispatch).
// PF=0 (QKV/FF2): round-7 single-buffer loop.
// Epilogue (bf16 out): repack C-tile through LDS -> dwordx4 256B stores.
// ---------------------------------------------------------------------------
template<int MI, int PF>
__global__ __launch_bounds__(256) void gemm_bt_t(const u16* __restrict__ A,
                                                 const u16* __restrict__ BT,
                                                 const float* __restrict__ bias,
                                                 void* __restrict__ C,
                                                 int M, int N, int K, int act, int ofp32)
{
    constexpr int TM = MI * 32;
    constexpr int HALF = TM * 64 + 128 * 64;       // u16 per buffer
    __shared__ __align__(16) u16 SM[(PF ? 2 : 1) * HALF];
    const int t = threadIdx.x;

    // XCD-aware remap (bijective), m fastest within XCD (R10)
    const int NX = gridDim.x, MY8 = gridDim.y >> 3;
    const int L = blockIdx.y * NX + blockIdx.x;
    const int xcd = L & 7, q = L >> 3;
    const long m0 = (long)(xcd * MY8 + q % MY8) * TM;
    const long n0 = (long)(q / MY8) * 128;

    const int lane = t & 63, w = t >> 6;
    const int wm = (w >> 1) * (MI * 16), wn = (w & 1) * 64;
    const int lr = lane & 15, lq = lane >> 4;

    // staging: thread t fills LDS slot t*16B = (row=t>>3, phys chunk=t&7);
    // fetches global logical chunk (t&7)^(row&7). (row+32p)&7 == row&7.
    const int r0 = t >> 3;                         // 0..31
    const int cg = ((t & 7) ^ (r0 & 7)) * 8;       // swizzled source column
    const u16* pa = &A[(m0 + r0) * (long)K + cg];
    const u16* pb = &BT[(n0 + r0) * (long)K + cg];

    f32x4 acc[MI][4] = {};
    const int NT = K >> 6;

    if constexpr (PF) {
        // prologue: stage tile 0 into buffer 0
        {
            char* la = (char*)SM + t * 16;
            char* lb = (char*)(SM + TM * 64) + t * 16;
            #pragma unroll
            for (int p = 0; p < MI; ++p) async16(pa + p * 32 * (long)K, la + p * 4096);
            #pragma unroll
            for (int p = 0; p < 4; ++p)  async16(pb + p * 32 * (long)K, lb + p * 4096);
        }
        __syncthreads();   // buffer 0 ready

        for (int kt = 0; kt < NT; ++kt) {
            const u16* As = SM + (kt & 1) * HALF;
            const u16* Bs = As + TM * 64;

            if (kt + 1 < NT) {
                char* la = (char*)(SM + ((kt + 1) & 1) * HALF) + t * 16;
                char* lb = la + TM * 64 * 2;
                const long kn = (long)(kt + 1) * 64;
                #pragma unroll
                for (int p = 0; p < MI; ++p) async16(pa + kn + p * 32 * (long)K, la + p * 4096);
                #pragma unroll
                for (int p = 0; p < 4; ++p)  async16(pb + kn + p * 32 * (long)K, lb + p * 4096);
            }

            #pragma unroll
            for (int ks = 0; ks < 2; ++ks) {
                const int kc = ((ks * 4 + lq) ^ (lr & 7)) * 8;
                bf16x8 af[MI], bfr[4];
                #pragma unroll
                for (int mi = 0; mi < MI; ++mi)
                    af[mi] = *(const bf16x8*)&As[(wm + mi * 16 + lr) * 64 + kc];
                #pragma unroll
                for (int ni = 0; ni < 4; ++ni)
                    bfr[ni] = *(const bf16x8*)&Bs[(wn + ni * 16 + lr) * 64 + kc];
                #pragma unroll
                for (int mi = 0; mi < MI; ++mi)
                    #pragma unroll
                    for (int ni = 0; ni < 4; ++ni)
                        acc[mi][ni] = __builtin_amdgcn_mfma_f32_16x16x32_bf16(
                            af[mi], bfr[ni], acc[mi][ni], 0, 0, 0);
            }
            __syncthreads();   // completes prefetch (a compute phase old)
        }
    } else {
        u16* As = SM;
        u16* Bs = SM + TM * 64;
        char* la = (char*)As + t * 16;
        char* lb = (char*)Bs + t * 16;
        for (int k0 = 0; k0 < K; k0 += 64) {
            #pragma unroll
            for (int p = 0; p < MI; ++p)
                async16(pa + k0 + p * 32 * (long)K, la + p * 4096);
            #pragma unroll
            for (int p = 0; p < 4; ++p)
                async16(pb + k0 + p * 32 * (long)K, lb + p * 4096);
            __syncthreads();
            #pragma unroll
            for (int ks = 0; ks < 2; ++ks) {
                const int kc = ((ks * 4 + lq) ^ (lr & 7)) * 8;
                bf16x8 af[MI], bfr[4];
                #pragma unroll
                for (int mi = 0; mi < MI; ++mi)
                    af[mi] = *(const bf16x8*)&As[(wm + mi * 16 + lr) * 64 + kc];
                #pragma unroll
                for (int ni = 0; ni < 4; ++ni)
                    bfr[ni] = *(const bf16x8*)&Bs[(wn + ni * 16 + lr) * 64 + kc];
                #pragma unroll
                for (int mi = 0; mi < MI; ++mi)
                    #pragma unroll
                    for (int ni = 0; ni < 4; ++ni)
                        acc[mi][ni] = __builtin_amdgcn_mfma_f32_16x16x32_bf16(
                            af[mi], bfr[ni], acc[mi][ni], 0, 0, 0);
            }
            __syncthreads();
        }
    }

    if (ofp32) {
        // fp32 path (FF2): direct stores, 64B segments - acceptable.
        #pragma unroll
        for (int mi = 0; mi < MI; ++mi) {
            #pragma unroll
            for (int ni = 0; ni < 4; ++ni) {
                const long colg = n0 + wn + ni * 16 + lr;
                const float bv = bias[colg];
                #pragma unroll
                for (int r = 0; r < 4; ++r) {
                    const long row = m0 + wm + mi * 16 + lq * 4 + r;
                    float v = acc[mi][ni][r] + bv;
                    if (act == 1) v = gelu_fast(v);
                    ((float*)C)[row * (long)N + colg] = v;
                }
            }
        }
    } else {
        // bf16 path: repack tile in LDS, then coalesced dwordx4 stores.
        u16* Cs = SM;
        #pragma unroll
        for (int mi = 0; mi < MI; ++mi) {
            #pragma unroll
            for (int ni = 0; ni < 4; ++ni) {
                const int col = wn + ni * 16 + lr;
                const float bv = bias[n0 + col];
                #pragma unroll
                for (int r = 0; r < 4; ++r) {
                    const int row = wm + mi * 16 + lq * 4 + r;
                    float v = acc[mi][ni][r] + bv;
                    if (act == 1) v = gelu_fast(v);
                    Cs[row * 128 + col] = f2bf(v);
                }
            }
        }
        __syncthreads();
        #pragma unroll
        for (int i = 0; i < MI * 2; ++i) {      // TM*128/8 vec / 256 thr
            const int v = i * 256 + t;
            const int row = v >> 4, c8 = (v & 15) * 8;
            uint4 qv = *(const uint4*)&Cs[row * 128 + c8];
            *(uint4*)&((u16*)C)[(m0 + row) * (long)N + n0 + c8] = qv;
        }
    }
}

// ---------------------------------------------------------------------------
// MFMA sliding-window attention. One block per (chunk c, head h, batch b).
// Round-7 version (best measured): static e-order V staging, in-place
// softmax, O repacked through LDS (reuses dead VT) -> uint4 128B stores.
// ---------------------------------------------------------------------------
__global__ __launch_bounds__(256) void attn_mfma(const u16* __restrict__ qkv,
                                                 u16* __restrict__ attn_out)
{
    const int c = blockIdx.x;   // 0..63
    const int h = blockIdx.y;   // 0..11
    const int b = blockIdx.z;   // 0..1
    const int t = threadIdx.x;
    const int wave = t >> 6, lane = t & 63;
    const int lr = lane & 15, lq = lane >> 4;

    __shared__ __align__(16) u16 Ps[64 * 200];
    __shared__ __align__(16) u16 VT[64 * 200];
    __shared__ float linv[64];

    const long base = (long)b * S_LEN;
    const long qrow0 = base + c * 64;

    // stage V^T (clamped rows)
    for (int v = t; v < 1536; v += 256) {
        int j = v >> 3, d8 = (v & 7) * 8;
        int s = c * 64 - 64 + j;
        int scl = s < 0 ? 0 : (s > S_LEN - 1 ? S_LEN - 1 : s);
        uint4 raw = *(const uint4*)&qkv[(base + scl) * (long)QKV_N + 2 * D_MODEL + h * 64 + d8];
        union { uint4 q; u16 el[8]; } u; u.q = raw;
        #pragma unroll
        for (int e = 0; e < 8; ++e) VT[(d8 + e) * 200 + j] = u.el[e];
    }

    // Q fragments direct from global
    bf16x8 aq[2];
    #pragma unroll
    for (int ks = 0; ks < 2; ++ks)
        aq[ks] = *(const bf16x8*)&qkv[(qrow0 + wave * 16 + lr) * (long)QKV_N
                                      + h * 64 + ks * 32 + lq * 8];

    // S = Q @ K^T (12 n-tiles x 16 keys)
    f32x4 sacc[12];
    #pragma unroll
    for (int nt = 0; nt < 12; ++nt) {
        int key = nt * 16 + lr;
        int s = c * 64 - 64 + key;
        int scl = s < 0 ? 0 : (s > S_LEN - 1 ? S_LEN - 1 : s);
        const u16* kp = &qkv[(base + scl) * (long)QKV_N + D_MODEL + h * 64 + lq * 8];
        bf16x8 bk0 = *(const bf16x8*)kp;
        bf16x8 bk1 = *(const bf16x8*)(kp + 32);
        f32x4 z = {0.f, 0.f, 0.f, 0.f};
        z = __builtin_amdgcn_mfma_f32_16x16x32_bf16(aq[0], bk0, z, 0, 0, 0);
        z = __builtin_amdgcn_mfma_f32_16x16x32_bf16(aq[1], bk1, z, 0, 0, 0);
        sacc[nt] = z;
    }

    // masked softmax in registers, in place on sacc
    // (C-layout: row=wave*16+lq*4+r, col=nt*16+lr)
    float m[4] = {-1e30f, -1e30f, -1e30f, -1e30f};
    #pragma unroll
    for (int nt = 0; nt < 12; ++nt) {
        const int j = nt * 16 + lr;
        const int gpos = c * 64 - 64 + j;
        #pragma unroll
        for (int r = 0; r < 4; ++r) {
            const int qi = wave * 16 + lq * 4 + r;
            const bool ok = (j >= qi) && (j <= qi + 128) && (gpos >= 0) && (gpos < S_LEN);
            const float v = ok ? sacc[nt][r] * 0.125f : -1e30f;
            sacc[nt][r] = v;
            m[r] = fmaxf(m[r], v);
        }
    }
    #pragma unroll
    for (int o = 1; o < 16; o <<= 1)
        #pragma unroll
        for (int r = 0; r < 4; ++r) m[r] = fmaxf(m[r], __shfl_xor(m[r], o));

    float sum[4] = {0.f, 0.f, 0.f, 0.f};
    #pragma unroll
    for (int nt = 0; nt < 12; ++nt)
        #pragma unroll
        for (int r = 0; r < 4; ++r) {
            const float e = __expf(sacc[nt][r] - m[r]);
            sacc[nt][r] = e;
            sum[r] += e;
        }
    #pragma unroll
    for (int o = 1; o < 16; o <<= 1)
        #pragma unroll
        for (int r = 0; r < 4; ++r) sum[r] += __shfl_xor(sum[r], o);

    #pragma unroll
    for (int nt = 0; nt < 12; ++nt)
        #pragma unroll
        for (int r = 0; r < 4; ++r)
            Ps[(wave * 16 + lq * 4 + r) * 200 + nt * 16 + lr] = f2bf(sacc[nt][r]);
    if (lr == 0) {
        #pragma unroll
        for (int r = 0; r < 4; ++r)
            linv[wave * 16 + lq * 4 + r] = 1.f / sum[r];
    }
    __syncthreads();

    // O = P @ V
    f32x4 oacc[4] = {};
    #pragma unroll
    for (int ks = 0; ks < 6; ++ks) {
        bf16x8 ap = *(const bf16x8*)&Ps[(wave * 16 + lr) * 200 + ks * 32 + lq * 8];
        #pragma unroll
        for (int nt = 0; nt < 4; ++nt) {
            bf16x8 bv = *(const bf16x8*)&VT[(nt * 16 + lr) * 200 + ks * 32 + lq * 8];
            oacc[nt] = __builtin_amdgcn_mfma_f32_16x16x32_bf16(ap, bv, oacc[nt], 0, 0, 0);
        }
    }

    // epilogue: repack O through LDS (VT dead after PV), then uint4 stores
    // at 128B row segments.
    __syncthreads();
    u16* Os = VT;   // 64 rows x 64 cols, stride 72 (conflict-light)
    #pragma unroll
    for (int nt = 0; nt < 4; ++nt) {
        #pragma unroll
        for (int r = 0; r < 4; ++r) {
            const int row = wave * 16 + lq * 4 + r;
            Os[row * 72 + nt * 16 + lr] = f2bf(oacc[nt][r] * linv[row]);
        }
    }
    __syncthreads();
    #pragma unroll
    for (int i = 0; i < 2; ++i) {
        const int v = i * 256 + t;
        const int row = v >> 3, c8 = (v & 7) * 8;
        uint4 qv = *(const uint4*)&Os[row * 72 + c8];
        *(uint4*)&attn_out[(qrow0 + row) * (long)D_MODEL + h * 64 + c8] = qv;
    }
}

// ---------------------------------------------------------------------------
// LayerNorm with fused residual: out = LN(a + b) * g + beta.
// One WAVE per row (4 rows/block): fully vectorized, wave-only shuffle
// reduction - no LDS, no __syncthreads.
// ---------------------------------------------------------------------------
__global__ __launch_bounds__(256) void ln_kernel(const void* a, int af32,
                                                 const u16* __restrict__ b,
                                                 const float* __restrict__ g,
                                                 const float* __restrict__ beta,
                                                 void* out, int of32)
{
    const int t = threadIdx.x;
    const int wv = t >> 6, lane = t & 63;
    const long r = (long)blockIdx.x * 4 + wv;
    const long rb = r * D_MODEL;

    float v[12];
    float s = 0.f, s2 = 0.f;
    #pragma unroll
    for (int k = 0; k < 3; ++k) {
        const long e0 = rb + k * 256 + lane * 4;
        float xa[4];
        if (af32) {
            float4 fa = *(const float4*)((const float*)a + e0);
            xa[0] = fa.x; xa[1] = fa.y; xa[2] = fa.z; xa[3] = fa.w;
        } else {
            union { uint2 u; u16 el[4]; } ua;
            ua.u = *(const uint2*)((const u16*)a + e0);
            #pragma unroll
            for (int j = 0; j < 4; ++j) xa[j] = bf2f(ua.el[j]);
        }
        union { uint2 u; u16 el[4]; } ub;
        ub.u = *(const uint2*)(b + e0);
        #pragma unroll
        for (int j = 0; j < 4; ++j) {
            const float xx = xa[j] + bf2f(ub.el[j]);
            v[k * 4 + j] = xx; s += xx; s2 += xx * xx;
        }
    }
    #pragma unroll
    for (int o = 32; o > 0; o >>= 1) {
        s  += __shfl_xor(s, o);
        s2 += __shfl_xor(s2, o);
    }
    const float mu   = s * (1.f / 768.f);
    const float var  = s2 * (1.f / 768.f) - mu * mu;
    const float rstd = rsqrtf(var + 1e-5f);

    #pragma unroll
    for (int k = 0; k < 3; ++k) {
        const long col = k * 256 + lane * 4;
        float4 g4 = *(const float4*)(g + col);
        float4 b4 = *(const float4*)(beta + col);
        float o0 = (v[k*4+0] - mu) * rstd * g4.x + b4.x;
        float o1 = (v[k*4+1] - mu) * rstd * g4.y + b4.y;
        float o2 = (v[k*4+2] - mu) * rstd * g4.z + b4.z;
        float o3 = (v[k*4+3] - mu) * rstd * g4.w + b4.w;
        if (of32) {
            float4 ov = {o0, o1, o2, o3};
            *(float4*)((float*)out + rb + col) = ov;
        } else {
            union { uint2 u; u16 el[4]; } uo;
            uo.el[0] = f2bf(o0); uo.el[1] = f2bf(o1);
            uo.el[2] = f2bf(o2); uo.el[3] = f2bf(o3);
            *(uint2*)((u16*)out + rb + col) = uo.u;
        }
    }
}

// ---------------------------------------------------------------------------
extern "C" void kernel_launch(void* const* d_in, const int* in_sizes, int n_in,
                              void* d_out, int out_size, void* d_ws, size_t ws_size,
                              hipStream_t stream)
{
    const float* x    = (const float*)d_in[0];
    const float* Wq   = (const float*)d_in[1];
    const float* bq   = (const float*)d_in[2];
    const float* Wk   = (const float*)d_in[3];
    const float* bk   = (const float*)d_in[4];
    const float* Wv   = (const float*)d_in[5];
    const float* bv   = (const float*)d_in[6];
    const float* ln1g = (const float*)d_in[7];
    const float* ln1b = (const float*)d_in[8];
    const float* W1   = (const float*)d_in[9];
    const float* b1   = (const float*)d_in[10];
    const float* W2   = (const float*)d_in[11];
    const float* b2   = (const float*)d_in[12];
    const float* ln2g = (const float*)d_in[13];
    const float* ln2b = (const float*)d_in[14];

    // workspace (~76 MB), liveness-aliased.
    char* ws = (char*)d_ws;
    size_t off = 0;
    u16* WqkvT  = (u16*)(ws + off);   off += (size_t)QKV_N * D_MODEL * 2;
    u16* W1T    = (u16*)(ws + off);   off += (size_t)FF_DIM * D_MODEL * 2;
    u16* W2T    = (u16*)(ws + off);   off += (size_t)D_MODEL * FF_DIM * 2;
    float* biasqkv = (float*)(ws + off); off += (size_t)QKV_N * 4;
    u16* big    = (u16*)(ws + off);   off += (size_t)M_ROWS * FF_DIM * 2;
    u16* x1     = (u16*)(ws + off);   off += (size_t)M_ROWS * D_MODEL * 2;

    u16* xbf    = big;
    u16* qkv    = big + (size_t)M_ROWS * D_MODEL;
    u16* hbuf   = big;
    u16* attnb  = (u16*)d_out;          // bf16 scratch in d_out, dead before FF2
    float* outf = (float*)d_out;

    dim3 blk(256);
    // fused prep: 1584 transpose tiles + 1 bias block + 768 cvt blocks
    prep<<<dim3(2353), blk, 0, stream>>>(x, Wq, Wk, Wv, W1, W2, bq, bk, bv,
                                         xbf, WqkvT, W1T, W2T, biasqkv);

    // qkv = x @ [Wq|Wk|Wv] + bias (bf16 out), 128x128 tile, single-buffer
    gemm_bt_t<4, 0><<<dim3(QKV_N / 128, M_ROWS / 128), blk, 0, stream>>>(
        xbf, WqkvT, biasqkv, qkv, M_ROWS, QKV_N, D_MODEL, 0, 0);
    // attention -> bf16 scratch in d_out
    attn_mfma<<<dim3(64, N_HEADS, B_SZ), blk, 0, stream>>>(qkv, attnb);
    // x1 = LN(attn + x)  (bf16 out), 1 wave/row
    ln_kernel<<<dim3(M_ROWS / 4), blk, 0, stream>>>(attnb, 0, xbf, ln1g, ln1b, x1, 0);
    // h = gelu(x1 @ W1 + b1)  (bf16 out), 128x128 tile, dbuf prefetch (A/B win)
    gemm_bt_t<4, 1><<<dim3(FF_DIM / 128, M_ROWS / 128), blk, 0, stream>>>(
        x1, W1T, b1, hbuf, M_ROWS, FF_DIM, D_MODEL, 1, 0);
    // ff = h @ W2 + b2 -> fp32 d_out, 64x128 tile, single-buffer
    gemm_bt_t<2, 0><<<dim3(D_MODEL / 128, M_ROWS / 64), blk, 0, stream>>>(
        hbuf, W2T, b2, outf, M_ROWS, D_MODEL, FF_DIM, 0, 1);
    // out = LN(ff + x1), fp32 in-place on d_out, 1 wave/row
    ln_kernel<<<dim3(M_ROWS / 4), blk, 0, stream>>>(outf, 1, x1, ln2g, ln2b, outf, 1);
}

// Round 12
// 310.927 us; speedup vs baseline: 1.0110x; 1.0110x over previous
//
#include <hip/hip_runtime.h>
#include <cstdint>
#include <cstddef>

#define S_LEN   4096
#define D_MODEL 768
#define N_HEADS 12
#define HEAD_DIM 64
#define FF_DIM  3072
#define B_SZ    2
#define M_ROWS  (B_SZ * S_LEN)   // 8192
#define QKV_N   (3 * D_MODEL)    // 2304

typedef unsigned short u16;
typedef __attribute__((ext_vector_type(8))) __bf16 bf16x8;
typedef __attribute__((ext_vector_type(4))) float  f32x4;

__device__ __forceinline__ float bf2f(u16 u) {
    union { unsigned u32; float f; } cv; cv.u32 = ((unsigned)u) << 16; return cv.f;
}
__device__ __forceinline__ u16 f2bf(float f) {
    __bf16 b = (__bf16)f;
    union { __bf16 b; u16 u; } cv; cv.b = b; return cv.u;
}
__device__ __forceinline__ float gelu_fast(float x) {
    float x2 = x * x;
    float u  = x * fmaf(0.035677408f, x2, 0.7978845608f);
    float e  = __expf(-2.f * u);
    return x * __builtin_amdgcn_rcpf(1.f + e);
}
// async global->LDS, 16B per lane. LDS dest is wave-uniform base + lane*16.
__device__ __forceinline__ void async16(const void* g, void* l) {
    __builtin_amdgcn_global_load_lds(
        (const __attribute__((address_space(1))) unsigned int*)g,
        (__attribute__((address_space(3))) unsigned int*)l, 16, 0, 0);
}

// ---------------------------------------------------------------------------
// PREP (one launch, 2353 blocks): fuses
//   - 3x weight transposes fp32[R,C] -> bf16[C,R]  (ids 0..1583, 64x64 tiles)
//   - qkv bias concat                              (id 1584)
//   - x fp32 -> bf16                               (ids 1585..2352)
// NOTE (R6 lesson): no per-lane rotated e-order (runtime el[] index ->
// scratch, rule #20). Static e-order kept.
// ---------------------------------------------------------------------------
__global__ __launch_bounds__(256) void prep(
    const float* __restrict__ x,
    const float* __restrict__ Wq, const float* __restrict__ Wk,
    const float* __restrict__ Wv,
    const float* __restrict__ W1, const float* __restrict__ W2,
    const float* __restrict__ bq, const float* __restrict__ bk,
    const float* __restrict__ bv,
    u16* __restrict__ xbf, u16* __restrict__ WqkvT, u16* __restrict__ W1T,
    u16* __restrict__ W2T, float* __restrict__ biasqkv)
{
    __shared__ __align__(16) u16 T[64 * 72];
    const int id = blockIdx.x;
    const int t = threadIdx.x;

    if (id < 1584) {
        // ---- transpose tile jobs ----
        const float* in; u16* o_; int C, R, tx, ty;
        if (id < 432) {
            const int z = id / 144, tile = id % 144;
            in = (z == 0) ? Wq : (z == 1) ? Wk : Wv;
            o_ = WqkvT + (size_t)z * 768 * 768;
            R = 768; C = 768; tx = tile % 12; ty = tile / 12;
        } else if (id < 1008) {
            const int tile = id - 432;
            in = W1; o_ = W1T; R = 768; C = 3072; tx = tile % 48; ty = tile / 48;
        } else {
            const int tile = id - 1008;
            in = W2; o_ = W2T; R = 3072; C = 768; tx = tile % 12; ty = tile / 12;
        }
        const int r0 = ty * 64, c0 = tx * 64;
        for (int v = t; v < 512; v += 256) {
            int rr = v >> 3, c8 = (v & 7) * 8;
            const float* p = in + (size_t)(r0 + rr) * C + c0 + c8;
            float4 a = *(const float4*)p;
            float4 b = *(const float4*)(p + 4);
            union { uint4 q; u16 el[8]; } o;
            o.el[0] = f2bf(a.x); o.el[1] = f2bf(a.y);
            o.el[2] = f2bf(a.z); o.el[3] = f2bf(a.w);
            o.el[4] = f2bf(b.x); o.el[5] = f2bf(b.y);
            o.el[6] = f2bf(b.z); o.el[7] = f2bf(b.w);
            *(uint4*)&T[rr * 72 + c8] = o.q;
        }
        __syncthreads();
        for (int v = t; v < 512; v += 256) {
            int cc = v >> 3, r8 = (v & 7) * 8;
            union { uint4 q; u16 el[8]; } tmp;
            #pragma unroll
            for (int e = 0; e < 8; ++e) tmp.el[e] = T[(r8 + e) * 72 + cc];
            *(uint4*)&o_[(size_t)(c0 + cc) * R + r0 + r8] = tmp.q;
        }
    } else if (id == 1584) {
        // ---- qkv bias concat ----
        for (int i = t; i < 768; i += 256) {
            biasqkv[i]        = bq[i];
            biasqkv[768 + i]  = bk[i];
            biasqkv[1536 + i] = bv[i];
        }
    } else {
        // ---- x fp32 -> bf16, 4 vec8 per thread ----
        const long c = id - 1585;
        #pragma unroll
        for (int j = 0; j < 4; ++j) {
            const long i = c * 1024 + j * 256 + t;   // vec8 index, < 786432
            const float* p = x + i * 8;
            float4 a = *(const float4*)p;
            float4 b = *(const float4*)(p + 4);
            union { uint4 q; u16 el[8]; } o;
            o.el[0] = f2bf(a.x); o.el[1] = f2bf(a.y);
            o.el[2] = f2bf(a.z); o.el[3] = f2bf(a.w);
            o.el[4] = f2bf(b.x); o.el[5] = f2bf(b.y);
            o.el[6] = f2bf(b.z); o.el[7] = f2bf(b.w);
            ((uint4*)xbf)[i] = o.q;
        }
    }
}

// ---------------------------------------------------------------------------
// MFMA GEMM: C[M,N] = A[M,K] @ BT[N,K]^T + bias, optional GELU.
// bf16 in, fp32 acc, output bf16 (ofp32=0) or fp32 (ofp32=1).
// Tile TM x 128 (TM = MI*32), BK=64, 4 waves in 2x2 quadrant layout.
// XOR-swizzled LDS chunks (conflict-free ds_read_b128).
//
// MF=1: m fastest within XCD (QKV/FF1 - weight matrix B is the reuse
// target; R10 measured FF1 FETCH 63->33 MB). MF=0: n fastest (FF2 - the
// 6 n-blocks share the dominant 50 MB A-panel; m-fastest separated them
// and cost ~4 us in R10). Both bijective.
//
// PF=1 (FF1): prefetch double-buffer (A/B-confirmed -2.5us/dispatch).
// PF=0 (QKV/FF2): single-buffer loop.
// Epilogue (bf16 out): repack C-tile through LDS -> dwordx4 256B stores.
// ---------------------------------------------------------------------------
template<int MI, int PF, int MF>
__global__ __launch_bounds__(256) void gemm_bt_t(const u16* __restrict__ A,
                                                 const u16* __restrict__ BT,
                                                 const float* __restrict__ bias,
                                                 void* __restrict__ C,
                                                 int M, int N, int K, int act, int ofp32)
{
    constexpr int TM = MI * 32;
    constexpr int HALF = TM * 64 + 128 * 64;       // u16 per buffer
    __shared__ __align__(16) u16 SM[(PF ? 2 : 1) * HALF];
    const int t = threadIdx.x;

    // XCD-aware remap (bijective)
    const int NX = gridDim.x, MY8 = gridDim.y >> 3;
    const int L = blockIdx.y * NX + blockIdx.x;
    const int xcd = L & 7, q = L >> 3;
    const long m0 = (long)(xcd * MY8 + (MF ? (q % MY8) : (q / NX))) * TM;
    const long n0 = (long)(MF ? (q / MY8) : (q % NX)) * 128;

    const int lane = t & 63, w = t >> 6;
    const int wm = (w >> 1) * (MI * 16), wn = (w & 1) * 64;
    const int lr = lane & 15, lq = lane >> 4;

    // staging: thread t fills LDS slot t*16B = (row=t>>3, phys chunk=t&7);
    // fetches global logical chunk (t&7)^(row&7). (row+32p)&7 == row&7.
    const int r0 = t >> 3;                         // 0..31
    const int cg = ((t & 7) ^ (r0 & 7)) * 8;       // swizzled source column
    const u16* pa = &A[(m0 + r0) * (long)K + cg];
    const u16* pb = &BT[(n0 + r0) * (long)K + cg];

    f32x4 acc[MI][4] = {};
    const int NT = K >> 6;

    if constexpr (PF) {
        // prologue: stage tile 0 into buffer 0
        {
            char* la = (char*)SM + t * 16;
            char* lb = (char*)(SM + TM * 64) + t * 16;
            #pragma unroll
            for (int p = 0; p < MI; ++p) async16(pa + p * 32 * (long)K, la + p * 4096);
            #pragma unroll
            for (int p = 0; p < 4; ++p)  async16(pb + p * 32 * (long)K, lb + p * 4096);
        }
        __syncthreads();   // buffer 0 ready

        for (int kt = 0; kt < NT; ++kt) {
            const u16* As = SM + (kt & 1) * HALF;
            const u16* Bs = As + TM * 64;

            if (kt + 1 < NT) {
                char* la = (char*)(SM + ((kt + 1) & 1) * HALF) + t * 16;
                char* lb = la + TM * 64 * 2;
                const long kn = (long)(kt + 1) * 64;
                #pragma unroll
                for (int p = 0; p < MI; ++p) async16(pa + kn + p * 32 * (long)K, la + p * 4096);
                #pragma unroll
                for (int p = 0; p < 4; ++p)  async16(pb + kn + p * 32 * (long)K, lb + p * 4096);
            }

            #pragma unroll
            for (int ks = 0; ks < 2; ++ks) {
                const int kc = ((ks * 4 + lq) ^ (lr & 7)) * 8;
                bf16x8 af[MI], bfr[4];
                #pragma unroll
                for (int mi = 0; mi < MI; ++mi)
                    af[mi] = *(const bf16x8*)&As[(wm + mi * 16 + lr) * 64 + kc];
                #pragma unroll
                for (int ni = 0; ni < 4; ++ni)
                    bfr[ni] = *(const bf16x8*)&Bs[(wn + ni * 16 + lr) * 64 + kc];
                #pragma unroll
                for (int mi = 0; mi < MI; ++mi)
                    #pragma unroll
                    for (int ni = 0; ni < 4; ++ni)
                        acc[mi][ni] = __builtin_amdgcn_mfma_f32_16x16x32_bf16(
                            af[mi], bfr[ni], acc[mi][ni], 0, 0, 0);
            }
            __syncthreads();   // completes prefetch (a compute phase old)
        }
    } else {
        u16* As = SM;
        u16* Bs = SM + TM * 64;
        char* la = (char*)As + t * 16;
        char* lb = (char*)Bs + t * 16;
        for (int k0 = 0; k0 < K; k0 += 64) {
            #pragma unroll
            for (int p = 0; p < MI; ++p)
                async16(pa + k0 + p * 32 * (long)K, la + p * 4096);
            #pragma unroll
            for (int p = 0; p < 4; ++p)
                async16(pb + k0 + p * 32 * (long)K, lb + p * 4096);
            __syncthreads();
            #pragma unroll
            for (int ks = 0; ks < 2; ++ks) {
                const int kc = ((ks * 4 + lq) ^ (lr & 7)) * 8;
                bf16x8 af[MI], bfr[4];
                #pragma unroll
                for (int mi = 0; mi < MI; ++mi)
                    af[mi] = *(const bf16x8*)&As[(wm + mi * 16 + lr) * 64 + kc];
                #pragma unroll
                for (int ni = 0; ni < 4; ++ni)
                    bfr[ni] = *(const bf16x8*)&Bs[(wn + ni * 16 + lr) * 64 + kc];
                #pragma unroll
                for (int mi = 0; mi < MI; ++mi)
                    #pragma unroll
                    for (int ni = 0; ni < 4; ++ni)
                        acc[mi][ni] = __builtin_amdgcn_mfma_f32_16x16x32_bf16(
                            af[mi], bfr[ni], acc[mi][ni], 0, 0, 0);
            }
            __syncthreads();
        }
    }

    if (ofp32) {
        // fp32 path (FF2): direct stores, 64B segments - acceptable.
        #pragma unroll
        for (int mi = 0; mi < MI; ++mi) {
            #pragma unroll
            for (int ni = 0; ni < 4; ++ni) {
                const long colg = n0 + wn + ni * 16 + lr;
                const float bv = bias[colg];
                #pragma unroll
                for (int r = 0; r < 4; ++r) {
                    const long row = m0 + wm + mi * 16 + lq * 4 + r;
                    float v = acc[mi][ni][r] + bv;
                    if (act == 1) v = gelu_fast(v);
                    ((float*)C)[row * (long)N + colg] = v;
                }
            }
        }
    } else {
        // bf16 path: repack tile in LDS, then coalesced dwordx4 stores.
        u16* Cs = SM;
        #pragma unroll
        for (int mi = 0; mi < MI; ++mi) {
            #pragma unroll
            for (int ni = 0; ni < 4; ++ni) {
                const int col = wn + ni * 16 + lr;
                const float bv = bias[n0 + col];
                #pragma unroll
                for (int r = 0; r < 4; ++r) {
                    const int row = wm + mi * 16 + lq * 4 + r;
                    float v = acc[mi][ni][r] + bv;
                    if (act == 1) v = gelu_fast(v);
                    Cs[row * 128 + col] = f2bf(v);
                }
            }
        }
        __syncthreads();
        #pragma unroll
        for (int i = 0; i < MI * 2; ++i) {      // TM*128/8 vec / 256 thr
            const int v = i * 256 + t;
            const int row = v >> 4, c8 = (v & 15) * 8;
            uint4 qv = *(const uint4*)&Cs[row * 128 + c8];
            *(uint4*)&((u16*)C)[(m0 + row) * (long)N + n0 + c8] = qv;
        }
    }
}

// ---------------------------------------------------------------------------
// MFMA sliding-window attention. One block per (chunk c, head h, batch b).
// R11: K staged into LDS via async16 (swizzled-linear, identical scheme to
// the GEMM staging that measures zero bank conflicts) - replaces the
// 12-iteration serial chain of scattered global K loads feeding QK^T.
// The K buffer aliases Ps (K dead after QK^T; barrier before Ps writes),
// keeping LDS at 51 KB -> 3 blocks/CU.
// V staging / softmax / PV / output repack: round-7 proven versions.
// ---------------------------------------------------------------------------
__global__ __launch_bounds__(256) void attn_mfma(const u16* __restrict__ qkv,
                                                 u16* __restrict__ attn_out)
{
    const int c = blockIdx.x;   // 0..63
    const int h = blockIdx.y;   // 0..11
    const int b = blockIdx.z;   // 0..1
    const int t = threadIdx.x;
    const int wave = t >> 6, lane = t & 63;
    const int lr = lane & 15, lq = lane >> 4;

    __shared__ __align__(16) u16 U[64 * 200];    // K (192x64 swz) then Ps
    __shared__ __align__(16) u16 VT[64 * 200];
    __shared__ float linv[64];

    const long base = (long)b * S_LEN;
    const long qrow0 = base + c * 64;

    // stage K (192 rows x 64, clamped) via async16, swizzled-linear:
    // slot id = it*256+t -> LDS byte id*16, row = id>>3, phys chunk = id&7,
    // global logical chunk = (id&7)^(row&7).
    #pragma unroll
    for (int it = 0; it < 6; ++it) {
        const int id = it * 256 + t;                 // 0..1535
        const int row = id >> 3;                     // 0..191
        const int cgk = ((id & 7) ^ (row & 7)) * 8;
        int s = c * 64 - 64 + row;
        int scl = s < 0 ? 0 : (s > S_LEN - 1 ? S_LEN - 1 : s);
        async16(&qkv[(base + scl) * (long)QKV_N + D_MODEL + h * 64 + cgk],
                (char*)U + id * 16);
    }

    // stage V^T (clamped rows), scalar scatter (R7 proven)
    for (int v = t; v < 1536; v += 256) {
        int j = v >> 3, d8 = (v & 7) * 8;
        int s = c * 64 - 64 + j;
        int scl = s < 0 ? 0 : (s > S_LEN - 1 ? S_LEN - 1 : s);
        uint4 raw = *(const uint4*)&qkv[(base + scl) * (long)QKV_N + 2 * D_MODEL + h * 64 + d8];
        union { uint4 q; u16 el[8]; } u; u.q = raw;
        #pragma unroll
        for (int e = 0; e < 8; ++e) VT[(d8 + e) * 200 + j] = u.el[e];
    }

    // Q fragments direct from global
    bf16x8 aq[2];
    #pragma unroll
    for (int ks = 0; ks < 2; ++ks)
        aq[ks] = *(const bf16x8*)&qkv[(qrow0 + wave * 16 + lr) * (long)QKV_N
                                      + h * 64 + ks * 32 + lq * 8];

    __syncthreads();   // K staged (implicit vmcnt(0)) + VT visible

    // S = Q @ K^T (12 n-tiles x 16 keys), K from LDS
    f32x4 sacc[12];
    #pragma unroll
    for (int nt = 0; nt < 12; ++nt) {
        const int key = nt * 16 + lr;
        bf16x8 bk0 = *(const bf16x8*)&U[key * 64 + ((lq) ^ (key & 7)) * 8];
        bf16x8 bk1 = *(const bf16x8*)&U[key * 64 + ((4 + lq) ^ (key & 7)) * 8];
        f32x4 z = {0.f, 0.f, 0.f, 0.f};
        z = __builtin_amdgcn_mfma_f32_16x16x32_bf16(aq[0], bk0, z, 0, 0, 0);
        z = __builtin_amdgcn_mfma_f32_16x16x32_bf16(aq[1], bk1, z, 0, 0, 0);
        sacc[nt] = z;
    }

    // masked softmax in registers, in place on sacc
    // (C-layout: row=wave*16+lq*4+r, col=nt*16+lr)
    float m[4] = {-1e30f, -1e30f, -1e30f, -1e30f};
    #pragma unroll
    for (int nt = 0; nt < 12; ++nt) {
        const int j = nt * 16 + lr;
        const int gpos = c * 64 - 64 + j;
        #pragma unroll
        for (int r = 0; r < 4; ++r) {
            const int qi = wave * 16 + lq * 4 + r;
            const bool ok = (j >= qi) && (j <= qi + 128) && (gpos >= 0) && (gpos < S_LEN);
            const float v = ok ? sacc[nt][r] * 0.125f : -1e30f;
            sacc[nt][r] = v;
            m[r] = fmaxf(m[r], v);
        }
    }
    #pragma unroll
    for (int o = 1; o < 16; o <<= 1)
        #pragma unroll
        for (int r = 0; r < 4; ++r) m[r] = fmaxf(m[r], __shfl_xor(m[r], o));

    float sum[4] = {0.f, 0.f, 0.f, 0.f};
    #pragma unroll
    for (int nt = 0; nt < 12; ++nt)
        #pragma unroll
        for (int r = 0; r < 4; ++r) {
            const float e = __expf(sacc[nt][r] - m[r]);
            sacc[nt][r] = e;
            sum[r] += e;
        }
    #pragma unroll
    for (int o = 1; o < 16; o <<= 1)
        #pragma unroll
        for (int r = 0; r < 4; ++r) sum[r] += __shfl_xor(sum[r], o);

    __syncthreads();   // all waves done reading K before Ps overwrites U

    u16* Ps = U;
    #pragma unroll
    for (int nt = 0; nt < 12; ++nt)
        #pragma unroll
        for (int r = 0; r < 4; ++r)
            Ps[(wave * 16 + lq * 4 + r) * 200 + nt * 16 + lr] = f2bf(sacc[nt][r]);
    if (lr == 0) {
        #pragma unroll
        for (int r = 0; r < 4; ++r)
            linv[wave * 16 + lq * 4 + r] = 1.f / sum[r];
    }
    __syncthreads();

    // O = P @ V
    f32x4 oacc[4] = {};
    #pragma unroll
    for (int ks = 0; ks < 6; ++ks) {
        bf16x8 ap = *(const bf16x8*)&Ps[(wave * 16 + lr) * 200 + ks * 32 + lq * 8];
        #pragma unroll
        for (int nt = 0; nt < 4; ++nt) {
            bf16x8 bv = *(const bf16x8*)&VT[(nt * 16 + lr) * 200 + ks * 32 + lq * 8];
            oacc[nt] = __builtin_amdgcn_mfma_f32_16x16x32_bf16(ap, bv, oacc[nt], 0, 0, 0);
        }
    }

    // epilogue: repack O through LDS (VT dead after PV), then uint4 stores
    // at 128B row segments.
    __syncthreads();
    u16* Os = VT;   // 64 rows x 64 cols, stride 72 (conflict-light)
    #pragma unroll
    for (int nt = 0; nt < 4; ++nt) {
        #pragma unroll
        for (int r = 0; r < 4; ++r) {
            const int row = wave * 16 + lq * 4 + r;
            Os[row * 72 + nt * 16 + lr] = f2bf(oacc[nt][r] * linv[row]);
        }
    }
    __syncthreads();
    #pragma unroll
    for (int i = 0; i < 2; ++i) {
        const int v = i * 256 + t;
        const int row = v >> 3, c8 = (v & 7) * 8;
        uint4 qv = *(const uint4*)&Os[row * 72 + c8];
        *(uint4*)&attn_out[(qrow0 + row) * (long)D_MODEL + h * 64 + c8] = qv;
    }
}

// ---------------------------------------------------------------------------
// LayerNorm with fused residual: out = LN(a + b) * g + beta.
// One WAVE per row (4 rows/block): fully vectorized, wave-only shuffle
// reduction - no LDS, no __syncthreads.
// ---------------------------------------------------------------------------
__global__ __launch_bounds__(256) void ln_kernel(const void* a, int af32,
                                                 const u16* __restrict__ b,
                                                 const float* __restrict__ g,
                                                 const float* __restrict__ beta,
                                                 void* out, int of32)
{
    const int t = threadIdx.x;
    const int wv = t >> 6, lane = t & 63;
    const long r = (long)blockIdx.x * 4 + wv;
    const long rb = r * D_MODEL;

    float v[12];
    float s = 0.f, s2 = 0.f;
    #pragma unroll
    for (int k = 0; k < 3; ++k) {
        const long e0 = rb + k * 256 + lane * 4;
        float xa[4];
        if (af32) {
            float4 fa = *(const float4*)((const float*)a + e0);
            xa[0] = fa.x; xa[1] = fa.y; xa[2] = fa.z; xa[3] = fa.w;
        } else {
            union { uint2 u; u16 el[4]; } ua;
            ua.u = *(const uint2*)((const u16*)a + e0);
            #pragma unroll
            for (int j = 0; j < 4; ++j) xa[j] = bf2f(ua.el[j]);
        }
        union { uint2 u; u16 el[4]; } ub;
        ub.u = *(const uint2*)(b + e0);
        #pragma unroll
        for (int j = 0; j < 4; ++j) {
            const float xx = xa[j] + bf2f(ub.el[j]);
            v[k * 4 + j] = xx; s += xx; s2 += xx * xx;
        }
    }
    #pragma unroll
    for (int o = 32; o > 0; o >>= 1) {
        s  += __shfl_xor(s, o);
        s2 += __shfl_xor(s2, o);
    }
    const float mu   = s * (1.f / 768.f);
    const float var  = s2 * (1.f / 768.f) - mu * mu;
    const float rstd = rsqrtf(var + 1e-5f);

    #pragma unroll
    for (int k = 0; k < 3; ++k) {
        const long col = k * 256 + lane * 4;
        float4 g4 = *(const float4*)(g + col);
        float4 b4 = *(const float4*)(beta + col);
        float o0 = (v[k*4+0] - mu) * rstd * g4.x + b4.x;
        float o1 = (v[k*4+1] - mu) * rstd * g4.y + b4.y;
        float o2 = (v[k*4+2] - mu) * rstd * g4.z + b4.z;
        float o3 = (v[k*4+3] - mu) * rstd * g4.w + b4.w;
        if (of32) {
            float4 ov = {o0, o1, o2, o3};
            *(float4*)((float*)out + rb + col) = ov;
        } else {
            union { uint2 u; u16 el[4]; } uo;
            uo.el[0] = f2bf(o0); uo.el[1] = f2bf(o1);
            uo.el[2] = f2bf(o2); uo.el[3] = f2bf(o3);
            *(uint2*)((u16*)out + rb + col) = uo.u;
        }
    }
}

// ---------------------------------------------------------------------------
extern "C" void kernel_launch(void* const* d_in, const int* in_sizes, int n_in,
                              void* d_out, int out_size, void* d_ws, size_t ws_size,
                              hipStream_t stream)
{
    const float* x    = (const float*)d_in[0];
    const float* Wq   = (const float*)d_in[1];
    const float* bq   = (const float*)d_in[2];
    const float* Wk   = (const float*)d_in[3];
    const float* bk   = (const float*)d_in[4];
    const float* Wv   = (const float*)d_in[5];
    const float* bv   = (const float*)d_in[6];
    const float* ln1g = (const float*)d_in[7];
    const float* ln1b = (const float*)d_in[8];
    const float* W1   = (const float*)d_in[9];
    const float* b1   = (const float*)d_in[10];
    const float* W2   = (const float*)d_in[11];
    const float* b2   = (const float*)d_in[12];
    const float* ln2g = (const float*)d_in[13];
    const float* ln2b = (const float*)d_in[14];

    // workspace (~76 MB), liveness-aliased.
    char* ws = (char*)d_ws;
    size_t off = 0;
    u16* WqkvT  = (u16*)(ws + off);   off += (size_t)QKV_N * D_MODEL * 2;
    u16* W1T    = (u16*)(ws + off);   off += (size_t)FF_DIM * D_MODEL * 2;
    u16* W2T    = (u16*)(ws + off);   off += (size_t)D_MODEL * FF_DIM * 2;
    float* biasqkv = (float*)(ws + off); off += (size_t)QKV_N * 4;
    u16* big    = (u16*)(ws + off);   off += (size_t)M_ROWS * FF_DIM * 2;
    u16* x1     = (u16*)(ws + off);   off += (size_t)M_ROWS * D_MODEL * 2;

    u16* xbf    = big;
    u16* qkv    = big + (size_t)M_ROWS * D_MODEL;
    u16* hbuf   = big;
    u16* attnb  = (u16*)d_out;          // bf16 scratch in d_out, dead before FF2
    float* outf = (float*)d_out;

    dim3 blk(256);
    // fused prep: 1584 transpose tiles + 1 bias block + 768 cvt blocks
    prep<<<dim3(2353), blk, 0, stream>>>(x, Wq, Wk, Wv, W1, W2, bq, bk, bv,
                                         xbf, WqkvT, W1T, W2T, biasqkv);

    // qkv = x @ [Wq|Wk|Wv] + bias (bf16 out), 128x128, single-buf, m-fastest
    gemm_bt_t<4, 0, 1><<<dim3(QKV_N / 128, M_ROWS / 128), blk, 0, stream>>>(
        xbf, WqkvT, biasqkv, qkv, M_ROWS, QKV_N, D_MODEL, 0, 0);
    // attention -> bf16 scratch in d_out
    attn_mfma<<<dim3(64, N_HEADS, B_SZ), blk, 0, stream>>>(qkv, attnb);
    // x1 = LN(attn + x)  (bf16 out), 1 wave/row
    ln_kernel<<<dim3(M_ROWS / 4), blk, 0, stream>>>(attnb, 0, xbf, ln1g, ln1b, x1, 0);
    // h = gelu(x1 @ W1 + b1)  (bf16 out), 128x128, dbuf prefetch, m-fastest
    gemm_bt_t<4, 1, 1><<<dim3(FF_DIM / 128, M_ROWS / 128), blk, 0, stream>>>(
        x1, W1T, b1, hbuf, M_ROWS, FF_DIM, D_MODEL, 1, 0);
    // ff = h @ W2 + b2 -> fp32 d_out, 64x128, single-buf, n-fastest
    gemm_bt_t<2, 0, 0><<<dim3(D_MODEL / 128, M_ROWS / 64), blk, 0, stream>>>(
        hbuf, W2T, b2, outf, M_ROWS, D_MODEL, FF_DIM, 0, 1);
    // out = LN(ff + x1), fp32 in-place on d_out, 1 wave/row
    ln_kernel<<<dim3(M_ROWS / 4), blk, 0, stream>>>(outf, 1, x1, ln2g, ln2b, outf, 1);
}

// Round 13
// 293.944 us; speedup vs baseline: 1.0694x; 1.0578x over previous
//
#include <hip/hip_runtime.h>
#include <cstdint>
#include <cstddef>

#define S_LEN   4096
#define D_MODEL 768
#define N_HEADS 12
#define HEAD_DIM 64
#define FF_DIM  3072
#define B_SZ    2
#define M_ROWS  (B_SZ * S_LEN)   // 8192
#define QKV_N   (3 * D_MODEL)    // 2304

typedef unsigned short u16;
typedef __attribute__((ext_vector_type(8))) __bf16 bf16x8;
typedef __attribute__((ext_vector_type(4))) float  f32x4;

__device__ __forceinline__ float bf2f(u16 u) {
    union { unsigned u32; float f; } cv; cv.u32 = ((unsigned)u) << 16; return cv.f;
}
__device__ __forceinline__ u16 f2bf(float f) {
    __bf16 b = (__bf16)f;
    union { __bf16 b; u16 u; } cv; cv.b = b; return cv.u;
}
__device__ __forceinline__ float gelu_fast(float x) {
    float x2 = x * x;
    float u  = x * fmaf(0.035677408f, x2, 0.7978845608f);
    float e  = __expf(-2.f * u);
    return x * __builtin_amdgcn_rcpf(1.f + e);
}
// async global->LDS, 16B per lane. LDS dest is wave-uniform base + lane*16.
__device__ __forceinline__ void async16(const void* g, void* l) {
    __builtin_amdgcn_global_load_lds(
        (const __attribute__((address_space(1))) unsigned int*)g,
        (__attribute__((address_space(3))) unsigned int*)l, 16, 0, 0);
}

// ---------------------------------------------------------------------------
// PREP (one launch, 2353 blocks): fuses
//   - 3x weight transposes fp32[R,C] -> bf16[C,R]  (ids 0..1583, 64x64 tiles)
//   - qkv bias concat                              (id 1584)
//   - x fp32 -> bf16                               (ids 1585..2352)
// NOTE (R6 lesson): no per-lane rotated e-order (runtime el[] index ->
// scratch, rule #20). Static e-order kept.
// ---------------------------------------------------------------------------
__global__ __launch_bounds__(256) void prep(
    const float* __restrict__ x,
    const float* __restrict__ Wq, const float* __restrict__ Wk,
    const float* __restrict__ Wv,
    const float* __restrict__ W1, const float* __restrict__ W2,
    const float* __restrict__ bq, const float* __restrict__ bk,
    const float* __restrict__ bv,
    u16* __restrict__ xbf, u16* __restrict__ WqkvT, u16* __restrict__ W1T,
    u16* __restrict__ W2T, float* __restrict__ biasqkv)
{
    __shared__ __align__(16) u16 T[64 * 72];
    const int id = blockIdx.x;
    const int t = threadIdx.x;

    if (id < 1584) {
        // ---- transpose tile jobs ----
        const float* in; u16* o_; int C, R, tx, ty;
        if (id < 432) {
            const int z = id / 144, tile = id % 144;
            in = (z == 0) ? Wq : (z == 1) ? Wk : Wv;
            o_ = WqkvT + (size_t)z * 768 * 768;
            R = 768; C = 768; tx = tile % 12; ty = tile / 12;
        } else if (id < 1008) {
            const int tile = id - 432;
            in = W1; o_ = W1T; R = 768; C = 3072; tx = tile % 48; ty = tile / 48;
        } else {
            const int tile = id - 1008;
            in = W2; o_ = W2T; R = 3072; C = 768; tx = tile % 12; ty = tile / 12;
        }
        const int r0 = ty * 64, c0 = tx * 64;
        for (int v = t; v < 512; v += 256) {
            int rr = v >> 3, c8 = (v & 7) * 8;
            const float* p = in + (size_t)(r0 + rr) * C + c0 + c8;
            float4 a = *(const float4*)p;
            float4 b = *(const float4*)(p + 4);
            union { uint4 q; u16 el[8]; } o;
            o.el[0] = f2bf(a.x); o.el[1] = f2bf(a.y);
            o.el[2] = f2bf(a.z); o.el[3] = f2bf(a.w);
            o.el[4] = f2bf(b.x); o.el[5] = f2bf(b.y);
            o.el[6] = f2bf(b.z); o.el[7] = f2bf(b.w);
            *(uint4*)&T[rr * 72 + c8] = o.q;
        }
        __syncthreads();
        for (int v = t; v < 512; v += 256) {
            int cc = v >> 3, r8 = (v & 7) * 8;
            union { uint4 q; u16 el[8]; } tmp;
            #pragma unroll
            for (int e = 0; e < 8; ++e) tmp.el[e] = T[(r8 + e) * 72 + cc];
            *(uint4*)&o_[(size_t)(c0 + cc) * R + r0 + r8] = tmp.q;
        }
    } else if (id == 1584) {
        // ---- qkv bias concat ----
        for (int i = t; i < 768; i += 256) {
            biasqkv[i]        = bq[i];
            biasqkv[768 + i]  = bk[i];
            biasqkv[1536 + i] = bv[i];
        }
    } else {
        // ---- x fp32 -> bf16, 4 vec8 per thread ----
        const long c = id - 1585;
        #pragma unroll
        for (int j = 0; j < 4; ++j) {
            const long i = c * 1024 + j * 256 + t;   // vec8 index, < 786432
            const float* p = x + i * 8;
            float4 a = *(const float4*)p;
            float4 b = *(const float4*)(p + 4);
            union { uint4 q; u16 el[8]; } o;
            o.el[0] = f2bf(a.x); o.el[1] = f2bf(a.y);
            o.el[2] = f2bf(a.z); o.el[3] = f2bf(a.w);
            o.el[4] = f2bf(b.x); o.el[5] = f2bf(b.y);
            o.el[6] = f2bf(b.z); o.el[7] = f2bf(b.w);
            ((uint4*)xbf)[i] = o.q;
        }
    }
}

// ---------------------------------------------------------------------------
// MFMA GEMM: C[M,N] = A[M,K] @ BT[N,K]^T + bias, optional GELU.
// bf16 in, fp32 acc, output bf16 (ofp32=0) or fp32 (ofp32=1).
// Tile TM x 128 (TM = MI*32), BK=64, 4 waves in 2x2 quadrant layout.
// XOR-swizzled LDS chunks (conflict-free ds_read_b128).
//
// MF=1: m fastest within XCD (FF1 - B=W1T 4.7MB > 4MB L2 thrashes under
// n-fastest; R10 measured FETCH 63->33 MB). MF=0: n fastest (QKV: B=3.5MB
// fits L2 either way, revert of unverified R11 change; FF2: the 6 n-blocks
// share the dominant A-panel). Both bijective.
//
// PF=1: prefetch double-buffer - FF1 (A/B-confirmed -2.5us/dispatch,
// 64KB -> 2 blocks/CU tolerated) and R13: FF2 (49KB keeps 3 blocks/CU,
// K=3072 = 48 staging-latency exposures to hide vs FF1's 12).
// PF=0 (QKV): single-buffer loop (dbuf at 64KB -> 2/CU regressed in R8).
// Epilogue (bf16 out): repack C-tile through LDS -> dwordx4 256B stores.
// ---------------------------------------------------------------------------
template<int MI, int PF, int MF>
__global__ __launch_bounds__(256) void gemm_bt_t(const u16* __restrict__ A,
                                                 const u16* __restrict__ BT,
                                                 const float* __restrict__ bias,
                                                 void* __restrict__ C,
                                                 int M, int N, int K, int act, int ofp32)
{
    constexpr int TM = MI * 32;
    constexpr int HALF = TM * 64 + 128 * 64;       // u16 per buffer
    __shared__ __align__(16) u16 SM[(PF ? 2 : 1) * HALF];
    const int t = threadIdx.x;

    // XCD-aware remap (bijective)
    const int NX = gridDim.x, MY8 = gridDim.y >> 3;
    const int L = blockIdx.y * NX + blockIdx.x;
    const int xcd = L & 7, q = L >> 3;
    const long m0 = (long)(xcd * MY8 + (MF ? (q % MY8) : (q / NX))) * TM;
    const long n0 = (long)(MF ? (q / MY8) : (q % NX)) * 128;

    const int lane = t & 63, w = t >> 6;
    const int wm = (w >> 1) * (MI * 16), wn = (w & 1) * 64;
    const int lr = lane & 15, lq = lane >> 4;

    // staging: thread t fills LDS slot t*16B = (row=t>>3, phys chunk=t&7);
    // fetches global logical chunk (t&7)^(row&7). (row+32p)&7 == row&7.
    const int r0 = t >> 3;                         // 0..31
    const int cg = ((t & 7) ^ (r0 & 7)) * 8;       // swizzled source column
    const u16* pa = &A[(m0 + r0) * (long)K + cg];
    const u16* pb = &BT[(n0 + r0) * (long)K + cg];

    f32x4 acc[MI][4] = {};
    const int NT = K >> 6;

    if constexpr (PF) {
        // prologue: stage tile 0 into buffer 0
        {
            char* la = (char*)SM + t * 16;
            char* lb = (char*)(SM + TM * 64) + t * 16;
            #pragma unroll
            for (int p = 0; p < MI; ++p) async16(pa + p * 32 * (long)K, la + p * 4096);
            #pragma unroll
            for (int p = 0; p < 4; ++p)  async16(pb + p * 32 * (long)K, lb + p * 4096);
        }
        __syncthreads();   // buffer 0 ready

        for (int kt = 0; kt < NT; ++kt) {
            const u16* As = SM + (kt & 1) * HALF;
            const u16* Bs = As + TM * 64;

            if (kt + 1 < NT) {
                char* la = (char*)(SM + ((kt + 1) & 1) * HALF) + t * 16;
                char* lb = la + TM * 64 * 2;
                const long kn = (long)(kt + 1) * 64;
                #pragma unroll
                for (int p = 0; p < MI; ++p) async16(pa + kn + p * 32 * (long)K, la + p * 4096);
                #pragma unroll
                for (int p = 0; p < 4; ++p)  async16(pb + kn + p * 32 * (long)K, lb + p * 4096);
            }

            #pragma unroll
            for (int ks = 0; ks < 2; ++ks) {
                const int kc = ((ks * 4 + lq) ^ (lr & 7)) * 8;
                bf16x8 af[MI], bfr[4];
                #pragma unroll
                for (int mi = 0; mi < MI; ++mi)
                    af[mi] = *(const bf16x8*)&As[(wm + mi * 16 + lr) * 64 + kc];
                #pragma unroll
                for (int ni = 0; ni < 4; ++ni)
                    bfr[ni] = *(const bf16x8*)&Bs[(wn + ni * 16 + lr) * 64 + kc];
                #pragma unroll
                for (int mi = 0; mi < MI; ++mi)
                    #pragma unroll
                    for (int ni = 0; ni < 4; ++ni)
                        acc[mi][ni] = __builtin_amdgcn_mfma_f32_16x16x32_bf16(
                            af[mi], bfr[ni], acc[mi][ni], 0, 0, 0);
            }
            __syncthreads();   // completes prefetch (a compute phase old)
        }
    } else {
        u16* As = SM;
        u16* Bs = SM + TM * 64;
        char* la = (char*)As + t * 16;
        char* lb = (char*)Bs + t * 16;
        for (int k0 = 0; k0 < K; k0 += 64) {
            #pragma unroll
            for (int p = 0; p < MI; ++p)
                async16(pa + k0 + p * 32 * (long)K, la + p * 4096);
            #pragma unroll
            for (int p = 0; p < 4; ++p)
                async16(pb + k0 + p * 32 * (long)K, lb + p * 4096);
            __syncthreads();
            #pragma unroll
            for (int ks = 0; ks < 2; ++ks) {
                const int kc = ((ks * 4 + lq) ^ (lr & 7)) * 8;
                bf16x8 af[MI], bfr[4];
                #pragma unroll
                for (int mi = 0; mi < MI; ++mi)
                    af[mi] = *(const bf16x8*)&As[(wm + mi * 16 + lr) * 64 + kc];
                #pragma unroll
                for (int ni = 0; ni < 4; ++ni)
                    bfr[ni] = *(const bf16x8*)&Bs[(wn + ni * 16 + lr) * 64 + kc];
                #pragma unroll
                for (int mi = 0; mi < MI; ++mi)
                    #pragma unroll
                    for (int ni = 0; ni < 4; ++ni)
                        acc[mi][ni] = __builtin_amdgcn_mfma_f32_16x16x32_bf16(
                            af[mi], bfr[ni], acc[mi][ni], 0, 0, 0);
            }
            __syncthreads();
        }
    }

    if (ofp32) {
        // fp32 path (FF2): direct stores, 64B segments - acceptable.
        #pragma unroll
        for (int mi = 0; mi < MI; ++mi) {
            #pragma unroll
            for (int ni = 0; ni < 4; ++ni) {
                const long colg = n0 + wn + ni * 16 + lr;
                const float bv = bias[colg];
                #pragma unroll
                for (int r = 0; r < 4; ++r) {
                    const long row = m0 + wm + mi * 16 + lq * 4 + r;
                    float v = acc[mi][ni][r] + bv;
                    if (act == 1) v = gelu_fast(v);
                    ((float*)C)[row * (long)N + colg] = v;
                }
            }
        }
    } else {
        // bf16 path: repack tile in LDS, then coalesced dwordx4 stores.
        u16* Cs = SM;
        #pragma unroll
        for (int mi = 0; mi < MI; ++mi) {
            #pragma unroll
            for (int ni = 0; ni < 4; ++ni) {
                const int col = wn + ni * 16 + lr;
                const float bv = bias[n0 + col];
                #pragma unroll
                for (int r = 0; r < 4; ++r) {
                    const int row = wm + mi * 16 + lq * 4 + r;
                    float v = acc[mi][ni][r] + bv;
                    if (act == 1) v = gelu_fast(v);
                    Cs[row * 128 + col] = f2bf(v);
                }
            }
        }
        __syncthreads();
        #pragma unroll
        for (int i = 0; i < MI * 2; ++i) {      // TM*128/8 vec / 256 thr
            const int v = i * 256 + t;
            const int row = v >> 4, c8 = (v & 15) * 8;
            uint4 qv = *(const uint4*)&Cs[row * 128 + c8];
            *(uint4*)&((u16*)C)[(m0 + row) * (long)N + n0 + c8] = qv;
        }
    }
}

// ---------------------------------------------------------------------------
// MFMA sliding-window attention. One block per (chunk c, head h, batch b).
// K staged into LDS via async16 (swizzled-linear); K buffer aliases Ps.
// V staging / softmax / PV / output repack: round-7 proven versions.
// ---------------------------------------------------------------------------
__global__ __launch_bounds__(256) void attn_mfma(const u16* __restrict__ qkv,
                                                 u16* __restrict__ attn_out)
{
    const int c = blockIdx.x;   // 0..63
    const int h = blockIdx.y;   // 0..11
    const int b = blockIdx.z;   // 0..1
    const int t = threadIdx.x;
    const int wave = t >> 6, lane = t & 63;
    const int lr = lane & 15, lq = lane >> 4;

    __shared__ __align__(16) u16 U[64 * 200];    // K (192x64 swz) then Ps
    __shared__ __align__(16) u16 VT[64 * 200];
    __shared__ float linv[64];

    const long base = (long)b * S_LEN;
    const long qrow0 = base + c * 64;

    // stage K (192 rows x 64, clamped) via async16, swizzled-linear
    #pragma unroll
    for (int it = 0; it < 6; ++it) {
        const int id = it * 256 + t;                 // 0..1535
        const int row = id >> 3;                     // 0..191
        const int cgk = ((id & 7) ^ (row & 7)) * 8;
        int s = c * 64 - 64 + row;
        int scl = s < 0 ? 0 : (s > S_LEN - 1 ? S_LEN - 1 : s);
        async16(&qkv[(base + scl) * (long)QKV_N + D_MODEL + h * 64 + cgk],
                (char*)U + id * 16);
    }

    // stage V^T (clamped rows), scalar scatter (R7 proven)
    for (int v = t; v < 1536; v += 256) {
        int j = v >> 3, d8 = (v & 7) * 8;
        int s = c * 64 - 64 + j;
        int scl = s < 0 ? 0 : (s > S_LEN - 1 ? S_LEN - 1 : s);
        uint4 raw = *(const uint4*)&qkv[(base + scl) * (long)QKV_N + 2 * D_MODEL + h * 64 + d8];
        union { uint4 q; u16 el[8]; } u; u.q = raw;
        #pragma unroll
        for (int e = 0; e < 8; ++e) VT[(d8 + e) * 200 + j] = u.el[e];
    }

    // Q fragments direct from global
    bf16x8 aq[2];
    #pragma unroll
    for (int ks = 0; ks < 2; ++ks)
        aq[ks] = *(const bf16x8*)&qkv[(qrow0 + wave * 16 + lr) * (long)QKV_N
                                      + h * 64 + ks * 32 + lq * 8];

    __syncthreads();   // K staged (implicit vmcnt(0)) + VT visible

    // S = Q @ K^T (12 n-tiles x 16 keys), K from LDS
    f32x4 sacc[12];
    #pragma unroll
    for (int nt = 0; nt < 12; ++nt) {
        const int key = nt * 16 + lr;
        bf16x8 bk0 = *(const bf16x8*)&U[key * 64 + ((lq) ^ (key & 7)) * 8];
        bf16x8 bk1 = *(const bf16x8*)&U[key * 64 + ((4 + lq) ^ (key & 7)) * 8];
        f32x4 z = {0.f, 0.f, 0.f, 0.f};
        z = __builtin_amdgcn_mfma_f32_16x16x32_bf16(aq[0], bk0, z, 0, 0, 0);
        z = __builtin_amdgcn_mfma_f32_16x16x32_bf16(aq[1], bk1, z, 0, 0, 0);
        sacc[nt] = z;
    }

    // masked softmax in registers, in place on sacc
    // (C-layout: row=wave*16+lq*4+r, col=nt*16+lr)
    float m[4] = {-1e30f, -1e30f, -1e30f, -1e30f};
    #pragma unroll
    for (int nt = 0; nt < 12; ++nt) {
        const int j = nt * 16 + lr;
        const int gpos = c * 64 - 64 + j;
        #pragma unroll
        for (int r = 0; r < 4; ++r) {
            const int qi = wave * 16 + lq * 4 + r;
            const bool ok = (j >= qi) && (j <= qi + 128) && (gpos >= 0) && (gpos < S_LEN);
            const float v = ok ? sacc[nt][r] * 0.125f : -1e30f;
            sacc[nt][r] = v;
            m[r] = fmaxf(m[r], v);
        }
    }
    #pragma unroll
    for (int o = 1; o < 16; o <<= 1)
        #pragma unroll
        for (int r = 0; r < 4; ++r) m[r] = fmaxf(m[r], __shfl_xor(m[r], o));

    float sum[4] = {0.f, 0.f, 0.f, 0.f};
    #pragma unroll
    for (int nt = 0; nt < 12; ++nt)
        #pragma unroll
        for (int r = 0; r < 4; ++r) {
            const float e = __expf(sacc[nt][r] - m[r]);
            sacc[nt][r] = e;
            sum[r] += e;
        }
    #pragma unroll
    for (int o = 1; o < 16; o <<= 1)
        #pragma unroll
        for (int r = 0; r < 4; ++r) sum[r] += __shfl_xor(sum[r], o);

    __syncthreads();   // all waves done reading K before Ps overwrites U

    u16* Ps = U;
    #pragma unroll
    for (int nt = 0; nt < 12; ++nt)
        #pragma unroll
        for (int r = 0; r < 4; ++r)
            Ps[(wave * 16 + lq * 4 + r) * 200 + nt * 16 + lr] = f2bf(sacc[nt][r]);
    if (lr == 0) {
        #pragma unroll
        for (int r = 0; r < 4; ++r)
            linv[wave * 16 + lq * 4 + r] = 1.f / sum[r];
    }
    __syncthreads();

    // O = P @ V
    f32x4 oacc[4] = {};
    #pragma unroll
    for (int ks = 0; ks < 6; ++ks) {
        bf16x8 ap = *(const bf16x8*)&Ps[(wave * 16 + lr) * 200 + ks * 32 + lq * 8];
        #pragma unroll
        for (int nt = 0; nt < 4; ++nt) {
            bf16x8 bv = *(const bf16x8*)&VT[(nt * 16 + lr) * 200 + ks * 32 + lq * 8];
            oacc[nt] = __builtin_amdgcn_mfma_f32_16x16x32_bf16(ap, bv, oacc[nt], 0, 0, 0);
        }
    }

    // epilogue: repack O through LDS (VT dead after PV), then uint4 stores
    // at 128B row segments.
    __syncthreads();
    u16* Os = VT;   // 64 rows x 64 cols, stride 72 (conflict-light)
    #pragma unroll
    for (int nt = 0; nt < 4; ++nt) {
        #pragma unroll
        for (int r = 0; r < 4; ++r) {
            const int row = wave * 16 + lq * 4 + r;
            Os[row * 72 + nt * 16 + lr] = f2bf(oacc[nt][r] * linv[row]);
        }
    }
    __syncthreads();
    #pragma unroll
    for (int i = 0; i < 2; ++i) {
        const int v = i * 256 + t;
        const int row = v >> 3, c8 = (v & 7) * 8;
        uint4 qv = *(const uint4*)&Os[row * 72 + c8];
        *(uint4*)&attn_out[(qrow0 + row) * (long)D_MODEL + h * 64 + c8] = qv;
    }
}

// ---------------------------------------------------------------------------
// LayerNorm with fused residual: out = LN(a + b) * g + beta.
// One WAVE per row (4 rows/block): fully vectorized, wave-only shuffle
// reduction - no LDS, no __syncthreads.
// ---------------------------------------------------------------------------
__global__ __launch_bounds__(256) void ln_kernel(const void* a, int af32,
                                                 const u16* __restrict__ b,
                                                 const float* __restrict__ g,
                                                 const float* __restrict__ beta,
                                                 void* out, int of32)
{
    const int t = threadIdx.x;
    const int wv = t >> 6, lane = t & 63;
    const long r = (long)blockIdx.x * 4 + wv;
    const long rb = r * D_MODEL;

    float v[12];
    float s = 0.f, s2 = 0.f;
    #pragma unroll
    for (int k = 0; k < 3; ++k) {
        const long e0 = rb + k * 256 + lane * 4;
        float xa[4];
        if (af32) {
            float4 fa = *(const float4*)((const float*)a + e0);
            xa[0] = fa.x; xa[1] = fa.y; xa[2] = fa.z; xa[3] = fa.w;
        } else {
            union { uint2 u; u16 el[4]; } ua;
            ua.u = *(const uint2*)((const u16*)a + e0);
            #pragma unroll
            for (int j = 0; j < 4; ++j) xa[j] = bf2f(ua.el[j]);
        }
        union { uint2 u; u16 el[4]; } ub;
        ub.u = *(const uint2*)(b + e0);
        #pragma unroll
        for (int j = 0; j < 4; ++j) {
            const float xx = xa[j] + bf2f(ub.el[j]);
            v[k * 4 + j] = xx; s += xx; s2 += xx * xx;
        }
    }
    #pragma unroll
    for (int o = 32; o > 0; o >>= 1) {
        s  += __shfl_xor(s, o);
        s2 += __shfl_xor(s2, o);
    }
    const float mu   = s * (1.f / 768.f);
    const float var  = s2 * (1.f / 768.f) - mu * mu;
    const float rstd = rsqrtf(var + 1e-5f);

    #pragma unroll
    for (int k = 0; k < 3; ++k) {
        const long col = k * 256 + lane * 4;
        float4 g4 = *(const float4*)(g + col);
        float4 b4 = *(const float4*)(beta + col);
        float o0 = (v[k*4+0] - mu) * rstd * g4.x + b4.x;
        float o1 = (v[k*4+1] - mu) * rstd * g4.y + b4.y;
        float o2 = (v[k*4+2] - mu) * rstd * g4.z + b4.z;
        float o3 = (v[k*4+3] - mu) * rstd * g4.w + b4.w;
        if (of32) {
            float4 ov = {o0, o1, o2, o3};
            *(float4*)((float*)out + rb + col) = ov;
        } else {
            union { uint2 u; u16 el[4]; } uo;
            uo.el[0] = f2bf(o0); uo.el[1] = f2bf(o1);
            uo.el[2] = f2bf(o2); uo.el[3] = f2bf(o3);
            *(uint2*)((u16*)out + rb + col) = uo.u;
        }
    }
}

// ---------------------------------------------------------------------------
extern "C" void kernel_launch(void* const* d_in, const int* in_sizes, int n_in,
                              void* d_out, int out_size, void* d_ws, size_t ws_size,
                              hipStream_t stream)
{
    const float* x    = (const float*)d_in[0];
    const float* Wq   = (const float*)d_in[1];
    const float* bq   = (const float*)d_in[2];
    const float* Wk   = (const float*)d_in[3];
    const float* bk   = (const float*)d_in[4];
    const float* Wv   = (const float*)d_in[5];
    const float* bv   = (const float*)d_in[6];
    const float* ln1g = (const float*)d_in[7];
    const float* ln1b = (const float*)d_in[8];
    const float* W1   = (const float*)d_in[9];
    const float* b1   = (const float*)d_in[10];
    const float* W2   = (const float*)d_in[11];
    const float* b2   = (const float*)d_in[12];
    const float* ln2g = (const float*)d_in[13];
    const float* ln2b = (const float*)d_in[14];

    // workspace (~76 MB), liveness-aliased.
    char* ws = (char*)d_ws;
    size_t off = 0;
    u16* WqkvT  = (u16*)(ws + off);   off += (size_t)QKV_N * D_MODEL * 2;
    u16* W1T    = (u16*)(ws + off);   off += (size_t)FF_DIM * D_MODEL * 2;
    u16* W2T    = (u16*)(ws + off);   off += (size_t)D_MODEL * FF_DIM * 2;
    float* biasqkv = (float*)(ws + off); off += (size_t)QKV_N * 4;
    u16* big    = (u16*)(ws + off);   off += (size_t)M_ROWS * FF_DIM * 2;
    u16* x1     = (u16*)(ws + off);   off += (size_t)M_ROWS * D_MODEL * 2;

    u16* xbf    = big;
    u16* qkv    = big + (size_t)M_ROWS * D_MODEL;
    u16* hbuf   = big;
    u16* attnb  = (u16*)d_out;          // bf16 scratch in d_out, dead before FF2
    float* outf = (float*)d_out;

    dim3 blk(256);
    // fused prep: 1584 transpose tiles + 1 bias block + 768 cvt blocks
    prep<<<dim3(2353), blk, 0, stream>>>(x, Wq, Wk, Wv, W1, W2, bq, bk, bv,
                                         xbf, WqkvT, W1T, W2T, biasqkv);

    // qkv = x @ [Wq|Wk|Wv] + bias (bf16 out), 128x128, single-buf, n-fastest
    gemm_bt_t<4, 0, 0><<<dim3(QKV_N / 128, M_ROWS / 128), blk, 0, stream>>>(
        xbf, WqkvT, biasqkv, qkv, M_ROWS, QKV_N, D_MODEL, 0, 0);
    // attention -> bf16 scratch in d_out
    attn_mfma<<<dim3(64, N_HEADS, B_SZ), blk, 0, stream>>>(qkv, attnb);
    // x1 = LN(attn + x)  (bf16 out), 1 wave/row
    ln_kernel<<<dim3(M_ROWS / 4), blk, 0, stream>>>(attnb, 0, xbf, ln1g, ln1b, x1, 0);
    // h = gelu(x1 @ W1 + b1)  (bf16 out), 128x128, dbuf prefetch, m-fastest
    gemm_bt_t<4, 1, 1><<<dim3(FF_DIM / 128, M_ROWS / 128), blk, 0, stream>>>(
        x1, W1T, b1, hbuf, M_ROWS, FF_DIM, D_MODEL, 1, 0);
    // ff = h @ W2 + b2 -> fp32 d_out, 64x128, dbuf prefetch (49KB = 3 blk/CU,
    // 48 K-tiles to hide), n-fastest
    gemm_bt_t<2, 1, 0><<<dim3(D_MODEL / 128, M_ROWS / 64), blk, 0, stream>>>(
        hbuf, W2T, b2, outf, M_ROWS, D_MODEL, FF_DIM, 0, 1);
    // out = LN(ff + x1), fp32 in-place on d_out, 1 wave/row
    ln_kernel<<<dim3(M_ROWS / 4), blk, 0, stream>>>(outf, 1, x1, ln2g, ln2b, outf, 1);
}